// Round 14
// baseline (193.017 us; speedup 1.0000x reference)
//
#include <hip/hip_runtime.h>
#include <hip/hip_bf16.h>

#define NN 51200
#define EE 819200
#define BB 64
#define NS 32
#define NPWG 4      // nodes per wave, global edge pass
#define NPWL 4      // nodes per wave, local edge pass
#define NBUCK 512   // dst-range buckets for scatter
#define NPB 100     // nodes per bucket = NN/NBUCK
#define CAP 4096    // bucket capacity (mean 1600, std ~40)
#define EPB 4096    // edges per block in bucketA multi-split

typedef __attribute__((ext_vector_type(8))) short short8;
typedef __attribute__((ext_vector_type(4))) float f32x4;

__device__ __forceinline__ ushort f2bf(float f) {
    unsigned int u = __float_as_uint(f);
    unsigned int r = (u + 0x7FFFu + ((u >> 16) & 1u)) >> 16;   // RNE, finite inputs
    return (ushort)r;
}
__device__ __forceinline__ unsigned int cvt_pk_bf16(float lo, float hi) {
    unsigned int r;
    asm("v_cvt_pk_bf16_f32 %0, %1, %2" : "=v"(r) : "v"(lo), "v"(hi));
    return r;
}
__device__ __forceinline__ float blo(unsigned int q) { return __uint_as_float(q << 16); }
__device__ __forceinline__ float bhi(unsigned int q) { return __uint_as_float(q & 0xFFFF0000u); }

// ---------------- weight prep ----------------
__global__ void prep_weights(const float* __restrict__ gW1, const float* __restrict__ lW1,
                             ushort* __restrict__ W1p, ushort* __restrict__ L1p) {
    int tid = threadIdx.x;
    for (int idx = tid; idx < 64 * 256; idx += 512) {
        int i = idx & 7, c = (idx >> 3) & 255, q = idx >> 11;
        int k = (q >> 2) * 32 + (q & 3) * 8 + i;
        W1p[idx] = f2bf(c < 128 ? gW1[k * 128 + c] : gW1[(64 + k) * 128 + (c - 128)]);
        L1p[idx] = f2bf(c < 128 ? lW1[k * 128 + c] : lW1[(128 + k) * 128 + (c - 128)]);
    }
}

// ---------------- CSR build: LDS multi-split -> fixed-capacity buckets -> in-LDS counting sort ----------------
__global__ __launch_bounds__(512) void bucketA_kernel(const int* __restrict__ eidx,
                                                      int* __restrict__ bcnt,
                                                      int2* __restrict__ btmp) {
    __shared__ int2 sp[EPB];         // 32 KB
    __shared__ ushort sb[EPB];       //  8 KB
    __shared__ ushort perm[EPB];     //  8 KB
    __shared__ int cnts[NBUCK];      //  2 KB
    __shared__ int lofs[NBUCK];      //  2 KB
    __shared__ int lcur[NBUCK];      //  2 KB
    const int tid = threadIdx.x;
    const int base = blockIdx.x * EPB;

    cnts[tid] = 0;
    __syncthreads();
    for (int i = tid; i < EPB; i += 512) {
        int d = eidx[EE + base + i], s = eidx[base + i];
        sp[i] = make_int2(s, d);
        int b = d / NPB;
        sb[i] = (ushort)b;
        atomicAdd(&cnts[b], 1);
    }
    __syncthreads();
    const int v = cnts[tid];
    lofs[tid] = v;
    __syncthreads();
    for (int o = 1; o < NBUCK; o <<= 1) {
        int u = (tid >= o) ? lofs[tid - o] : 0;
        __syncthreads();
        lofs[tid] += u;
        __syncthreads();
    }
    const int excl = lofs[tid] - v;
    lofs[tid] = excl;
    lcur[tid] = excl;
    const int mygbase = (v > 0) ? atomicAdd(&bcnt[tid * 16], v) : 0;
    __syncthreads();
    for (int i = tid; i < EPB; i += 512) {
        int pos = atomicAdd(&lcur[sb[i]], 1);
        perm[pos] = (ushort)i;
    }
    __syncthreads();
    {
        const int c = cnts[tid];
        const int lo = lofs[tid];
        int2* dst = btmp + (long)tid * CAP + mygbase;
        for (int j = 0; j < c; ++j) dst[j] = sp[perm[lo + j]];
    }
}

__global__ __launch_bounds__(512) void bucket_scan_kernel(const int* __restrict__ bcnt,
                                                          int* __restrict__ bbase) {
    __shared__ int s[NBUCK];
    const int t = threadIdx.x;
    int v = bcnt[t * 16];
    s[t] = v;
    __syncthreads();
    for (int o = 1; o < NBUCK; o <<= 1) {
        int u = (t >= o) ? s[t - o] : 0;
        __syncthreads();
        s[t] += u;
        __syncthreads();
    }
    bbase[t] = s[t] - v;   // exclusive
}

__global__ __launch_bounds__(256) void bucketB_kernel(const int2* __restrict__ btmp,
                                                      const int* __restrict__ bcnt,
                                                      const int* __restrict__ bbase,
                                                      int* __restrict__ offs,
                                                      int* __restrict__ csr) {
    __shared__ int lcnt[NPB];
    __shared__ int lofs[NPB];
    __shared__ int lcur[NPB];
    __shared__ int2 pairs[2048];
    const int bkt = blockIdx.x, tid = threadIdx.x;
    const int cnt = bcnt[bkt * 16];
    const int base = bbase[bkt];
    for (int j = tid; j < NPB; j += 256) lcnt[j] = 0;
    __syncthreads();
    for (int i = tid; i < cnt; i += 256) {
        int2 p = btmp[(long)bkt * CAP + i];
        if (i < 2048) pairs[i] = p;
        atomicAdd(&lcnt[p.y - bkt * NPB], 1);
    }
    __syncthreads();
    if (tid == 0) {
        int run = base;
        for (int j = 0; j < NPB; ++j) { lofs[j] = run; run += lcnt[j]; }
    }
    __syncthreads();
    for (int j = tid; j < NPB; j += 256) {
        lcur[j] = lofs[j];
        offs[bkt * NPB + j] = lofs[j];
    }
    if (bkt == NBUCK - 1 && tid == 0) offs[NN] = EE;
    __syncthreads();
    for (int i = tid; i < cnt; i += 256) {
        int2 p = (i < 2048) ? pairs[i] : btmp[(long)bkt * CAP + i];
        int pos = atomicAdd(&lcur[p.y - bkt * NPB], 1);
        csr[pos] = p.x;
    }
}

// ---------------- node-table GEMM: out[n][0:256] = bf16( x[n]@Wcat + bias_fold + T12[batch[n]] ) ----------------
__global__ __launch_bounds__(512) void pq_gemm(
        const float* __restrict__ x, const ushort* __restrict__ Wp,
        const float* __restrict__ bias1, const float* __restrict__ T12,
        const int* __restrict__ batch, ushort* __restrict__ out) {
    const int tid = threadIdx.x;
    const int w = tid >> 6, l = tid & 63, lr = l & 15, lg = l >> 4;
    const int node = blockIdx.x * 128 + w * 16 + lr;

    short8 xa[2];
#pragma unroll
    for (int ks = 0; ks < 2; ++ks) {
        const float4* bp = reinterpret_cast<const float4*>(x + (long)node * 64 + ks * 32 + lg * 8);
        float4 f0 = bp[0], f1 = bp[1];
        union { short8 s; unsigned int u[4]; } t;
        t.u[0] = cvt_pk_bf16(f0.x, f0.y);
        t.u[1] = cvt_pk_bf16(f0.z, f0.w);
        t.u[2] = cvt_pk_bf16(f1.x, f1.y);
        t.u[3] = cvt_pk_bf16(f1.z, f1.w);
        xa[ks] = t.s;
    }
    f32x4 acc[16];
#pragma unroll
    for (int t = 0; t < 16; ++t)
#pragma unroll
        for (int i = 0; i < 4; ++i)
            acc[t][i] = (t < 8) ? bias1[t * 16 + lg * 4 + i] : 0.f;
#pragma unroll
    for (int ks = 0; ks < 2; ++ks)
#pragma unroll
        for (int t = 0; t < 16; ++t) {
            short8 wf = *reinterpret_cast<const short8*>(Wp + (((ks * 4 + lg) * 256) + t * 16 + lr) * 8);
            acc[t] = __builtin_amdgcn_mfma_f32_16x16x32_bf16(wf, xa[ks], acc[t], 0, 0, 0);
        }
    if (T12) {
        const float* tp = T12 + (long)batch[node] * 256;
#pragma unroll
        for (int t = 0; t < 16; ++t)
#pragma unroll
            for (int i = 0; i < 4; ++i)
                acc[t][i] += tp[t * 16 + lg * 4 + i];
    }
#pragma unroll
    for (int t = 0; t < 16; ++t) {
        uint2 v;
        v.x = cvt_pk_bf16(acc[t][0], acc[t][1]);
        v.y = cvt_pk_bf16(acc[t][2], acc[t][3]);
        *reinterpret_cast<uint2*>(out + (long)node * 256 + t * 16 + lg * 4) = v;
    }
}

// ---------------- global edge pass: 2 edges/load (dwordx2), 4ch/lane, scalar control ----------------
__global__ __launch_bounds__(256) void global_edge(
        const ushort* __restrict__ PQ, const int* __restrict__ csr,
        const int* __restrict__ offs, const float* __restrict__ e,
        const int* __restrict__ batch,
        float* __restrict__ hidpart, float* __restrict__ esumpart) {
    const int tid = threadIdx.x;
    const int w = tid >> 6, l = tid & 63, c = l & 31;
    const bool hi = l >= 32;
    const int wid = blockIdx.x * 4 + w;
    const int node0 = __builtin_amdgcn_readfirstlane(wid * NPWG);
    const int slot = wid & (NS - 1);

    float accp[4] = {0.f, 0.f, 0.f, 0.f};
    float eacc = 0.f;
    int curb = batch[node0];

    for (int n = 0; n < NPWG; ++n) {
        const int node = node0 + n;
        const int off  = offs[node];
        const int cnt  = offs[node + 1] - off;
        const int bb   = batch[node];
        const float ev = e[node];
        if (bb != curb) {
#pragma unroll
            for (int j = 0; j < 4; ++j) accp[j] += __shfl_xor(accp[j], 32, 64);
            float* hp = hidpart + (long)slot * (BB * 128) + curb * 128 + 4 * c;
            if (!hi) {
#pragma unroll
                for (int j = 0; j < 4; ++j) atomicAdd(hp + j, accp[j]);
            }
            if (l == 0) atomicAdd(&esumpart[slot * BB + curb], eacc);
#pragma unroll
            for (int j = 0; j < 4; ++j) accp[j] = 0.f;
            eacc = 0.f;
            curb = bb;
        }
        if (cnt <= 0) continue;
        const uint2 pdu = *reinterpret_cast<const uint2*>(PQ + (long)node * 256 + 4 * c);
        const float pv0 = blo(pdu.x), pv1 = bhi(pdu.x), pv2 = blo(pdu.y), pv3 = bhi(pdu.y);
        float h0 = 0.f, h1 = 0.f, h2 = 0.f, h3 = 0.f;
        int g = 0;
        for (; g + 16 <= cnt; g += 16) {        // 8 dwordx2 loads = 16 edges in flight
            uint2 qv[8];
#pragma unroll
            for (int k = 0; k < 8; ++k) {
                const int sa = csr[off + g + 2 * k];       // scalar (uniform addr)
                const int sb = csr[off + g + 2 * k + 1];
                const int s = hi ? sb : sa;                // 1 cndmask
                qv[k] = *reinterpret_cast<const uint2*>(PQ + (long)s * 256 + 128 + 4 * c);
            }
#pragma unroll
            for (int k = 0; k < 8; ++k) {
                h0 += fmaxf(pv0 + blo(qv[k].x), 0.f);
                h1 += fmaxf(pv1 + bhi(qv[k].x), 0.f);
                h2 += fmaxf(pv2 + blo(qv[k].y), 0.f);
                h3 += fmaxf(pv3 + bhi(qv[k].y), 0.f);
            }
        }
        for (; g + 2 <= cnt; g += 2) {          // pair tail
            const int sa = csr[off + g], sb = csr[off + g + 1];
            const int s = hi ? sb : sa;
            const uint2 q = *reinterpret_cast<const uint2*>(PQ + (long)s * 256 + 128 + 4 * c);
            h0 += fmaxf(pv0 + blo(q.x), 0.f);
            h1 += fmaxf(pv1 + bhi(q.x), 0.f);
            h2 += fmaxf(pv2 + blo(q.y), 0.f);
            h3 += fmaxf(pv3 + bhi(q.y), 0.f);
        }
        if (g < cnt) {                          // odd last edge: hi half contributes 0
            const int s = csr[off + g];
            const uint2 q = *reinterpret_cast<const uint2*>(PQ + (long)s * 256 + 128 + 4 * c);
            if (!hi) {
                h0 += fmaxf(pv0 + blo(q.x), 0.f);
                h1 += fmaxf(pv1 + bhi(q.x), 0.f);
                h2 += fmaxf(pv2 + blo(q.y), 0.f);
                h3 += fmaxf(pv3 + bhi(q.y), 0.f);
            }
        }
        accp[0] += ev * h0; accp[1] += ev * h1; accp[2] += ev * h2; accp[3] += ev * h3;
        eacc += ev * (float)cnt;
    }
    {   // final flush
#pragma unroll
        for (int j = 0; j < 4; ++j) accp[j] += __shfl_xor(accp[j], 32, 64);
        float* hp = hidpart + (long)slot * (BB * 128) + curb * 128 + 4 * c;
        if (!hi) {
#pragma unroll
            for (int j = 0; j < 4; ++j) atomicAdd(hp + j, accp[j]);
        }
        if (l == 0) atomicAdd(&esumpart[slot * BB + curb], eacc);
    }
}

// ---------------- fused: hidsum reduce -> pooled (LDS only) -> T12 ----------------
__global__ __launch_bounds__(256) void pooled_t12_kernel(
        const float* __restrict__ hidpart, const float* __restrict__ esumpart,
        const float* __restrict__ gW2, const float* __restrict__ gb2,
        const float* __restrict__ lW1, float* __restrict__ T12) {
    __shared__ float hs[128];
    __shared__ float qacc[4][64];
    __shared__ float pb[64];
    __shared__ float esv;
    const int b = blockIdx.x, tid = threadIdx.x;
    if (tid < 128) {
        float s = 0.f;
        for (int sl = 0; sl < NS; ++sl) s += hidpart[(long)sl * (BB * 128) + b * 128 + tid];
        hs[tid] = s;
    } else if (tid == 128) {
        float s = 0.f;
        for (int sl = 0; sl < NS; ++sl) s += esumpart[sl * BB + b];
        esv = s;
    }
    __syncthreads();
    {
        int col = tid & 63, qr = tid >> 6;
        float a = 0.f;
        for (int k = qr * 32; k < qr * 32 + 32; ++k) a += hs[k] * gW2[k * 64 + col];
        qacc[qr][col] = a;
    }
    __syncthreads();
    if (tid < 64) pb[tid] = qacc[0][tid] + qacc[1][tid] + qacc[2][tid] + qacc[3][tid] + esv * gb2[tid];
    __syncthreads();
    const float* col = (tid < 128) ? (lW1 + 64 * 128 + tid) : (lW1 + 192 * 128 + (tid - 128));
    float acc = 0.f;
    for (int k = 0; k < 64; ++k) acc += pb[k] * col[k * 128];
    T12[b * 256 + tid] = acc;
}

// ---------------- local edge pass: 2 edges/load (dwordx2), 4ch/lane, scalar control ----------------
__global__ __launch_bounds__(256) void local_edge(
        const ushort* __restrict__ PQL, const int* __restrict__ csr,
        const int* __restrict__ offs, const float* __restrict__ lW2,
        const float* __restrict__ lb2, float* __restrict__ out) {
    const int tid = threadIdx.x;
    const int w = tid >> 6, l = tid & 63, c = l & 31;
    const bool hi = l >= 32;
    const int wid = blockIdx.x * 4 + w;
    const int node0 = __builtin_amdgcn_readfirstlane(wid * NPWL);
    const float4 w4 = *reinterpret_cast<const float4*>(lW2 + 4 * c);
    const float b2v = lb2[0];

    for (int n = 0; n < NPWL; ++n) {
        const int node = node0 + n;
        const int off = offs[node];
        const int cnt = offs[node + 1] - off;
        float dacc = 0.f;
        if (cnt > 0) {
            const uint2 pdu = *reinterpret_cast<const uint2*>(PQL + (long)node * 256 + 4 * c);
            const float pv0 = blo(pdu.x), pv1 = bhi(pdu.x), pv2 = blo(pdu.y), pv3 = bhi(pdu.y);
            int g = 0;
            for (; g + 16 <= cnt; g += 16) {
                uint2 qv[8];
#pragma unroll
                for (int k = 0; k < 8; ++k) {
                    const int sa = csr[off + g + 2 * k];
                    const int sb = csr[off + g + 2 * k + 1];
                    const int s = hi ? sb : sa;
                    qv[k] = *reinterpret_cast<const uint2*>(PQL + (long)s * 256 + 128 + 4 * c);
                }
#pragma unroll
                for (int k = 0; k < 8; ++k) {
                    dacc += fmaxf(pv0 + blo(qv[k].x), 0.f) * w4.x
                          + fmaxf(pv1 + bhi(qv[k].x), 0.f) * w4.y
                          + fmaxf(pv2 + blo(qv[k].y), 0.f) * w4.z
                          + fmaxf(pv3 + bhi(qv[k].y), 0.f) * w4.w;
                }
            }
            for (; g + 2 <= cnt; g += 2) {
                const int sa = csr[off + g], sb = csr[off + g + 1];
                const int s = hi ? sb : sa;
                const uint2 q = *reinterpret_cast<const uint2*>(PQL + (long)s * 256 + 128 + 4 * c);
                dacc += fmaxf(pv0 + blo(q.x), 0.f) * w4.x
                      + fmaxf(pv1 + bhi(q.x), 0.f) * w4.y
                      + fmaxf(pv2 + blo(q.y), 0.f) * w4.z
                      + fmaxf(pv3 + bhi(q.y), 0.f) * w4.w;
            }
            if (g < cnt) {                      // odd last edge: hi half contributes 0
                const int s = csr[off + g];
                const uint2 q = *reinterpret_cast<const uint2*>(PQL + (long)s * 256 + 128 + 4 * c);
                if (!hi) {
                    dacc += fmaxf(pv0 + blo(q.x), 0.f) * w4.x
                          + fmaxf(pv1 + bhi(q.x), 0.f) * w4.y
                          + fmaxf(pv2 + blo(q.y), 0.f) * w4.z
                          + fmaxf(pv3 + bhi(q.y), 0.f) * w4.w;
                }
            }
            dacc += __shfl_xor(dacc, 1, 64);
            dacc += __shfl_xor(dacc, 2, 64);
            dacc += __shfl_xor(dacc, 4, 64);
            dacc += __shfl_xor(dacc, 8, 64);
            dacc += __shfl_xor(dacc, 16, 64);
            dacc += __shfl_xor(dacc, 32, 64);
        }
        if (l == 0) out[node] = dacc + (float)cnt * b2v;
    }
}

extern "C" void kernel_launch(void* const* d_in, const int* in_sizes, int n_in,
                              void* d_out, int out_size, void* d_ws, size_t ws_size,
                              hipStream_t stream) {
    const float* x   = (const float*)d_in[0];
    const float* e   = (const float*)d_in[1];
    const int*   ei  = (const int*)d_in[2];
    const int*   bat = (const int*)d_in[3];
    const float* gW1 = (const float*)d_in[4];
    const float* gb1 = (const float*)d_in[5];
    const float* gW2 = (const float*)d_in[6];
    const float* gb2 = (const float*)d_in[7];
    const float* lW1 = (const float*)d_in[8];
    const float* lb1 = (const float*)d_in[9];
    const float* lW2 = (const float*)d_in[10];
    const float* lb2 = (const float*)d_in[11];

    char* ws = (char*)d_ws;
    ushort* W1p     = (ushort*)(ws);                     //    32768 B
    ushort* L1p     = (ushort*)(ws + 32768);             //    32768 B
    float*  T12     = (float*)(ws + 65536);              //    65536 B
    float*  esumpart= (float*)(ws + 131072);             //     8192 B
    float*  hidpart = (float*)(ws + 139264);             //  1048576 B
    int*    offs    = (int*)(ws + 1187840);              //   204832 B (51201 ints)
    int*    bcnt    = (int*)(ws + 1392672);              //    32768 B (512 line-padded)
    int*    bbase   = (int*)(ws + 1425440);              //     2048 B
    int*    csr     = (int*)(ws + 1427488);              //  3276800 B
    ushort* PQ      = (ushort*)(ws + 4704288);           // 26214400 B (btmp overlays; reused for PQL)
    int2*   btmp    = (int2*)PQ;                         // 512*4096*8 = 16777216 B, consumed before pq_gemm

    hipMemsetAsync(bcnt, 0, 32768, stream);
    hipMemsetAsync(esumpart, 0, 8192 + 1048576, stream);           // esumpart + hidpart
    hipMemsetAsync(d_out, 0, (size_t)out_size * sizeof(float), stream);

    prep_weights<<<1, 512, 0, stream>>>(gW1, lW1, W1p, L1p);
    bucketA_kernel<<<EE / EPB, 512, 0, stream>>>(ei, bcnt, btmp);
    bucket_scan_kernel<<<1, NBUCK, 0, stream>>>(bcnt, bbase);
    bucketB_kernel<<<NBUCK, 256, 0, stream>>>(btmp, bcnt, bbase, offs, csr);

    pq_gemm<<<NN / 128, 512, 0, stream>>>(x, W1p, gb1, nullptr, bat, PQ);
    global_edge<<<NN / (4 * NPWG), 256, 0, stream>>>(PQ, csr, offs, e, bat, hidpart, esumpart);
    pooled_t12_kernel<<<BB, 256, 0, stream>>>(hidpart, esumpart, gW2, gb2, lW1, T12);
    pq_gemm<<<NN / 128, 512, 0, stream>>>(x, L1p, lb1, T12, bat, PQ);   // -> PQL
    local_edge<<<NN / (4 * NPWL), 256, 0, stream>>>(PQ, csr, offs, lW2, lb2, (float*)d_out);
}

// Round 15
// 180.056 us; speedup vs baseline: 1.0720x; 1.0720x over previous
//
#include <hip/hip_runtime.h>
#include <hip/hip_bf16.h>

#define NN 51200
#define EE 819200
#define BB 64
#define NS 32
#define NPWG 4      // nodes per wave, global edge pass
#define NPWL 4      // nodes per wave, local edge pass
#define NBUCK 512   // dst-range buckets for scatter
#define NPB 100     // nodes per bucket = NN/NBUCK
#define CAP 4096    // bucket capacity (mean 1600, std ~40)
#define EPB 4096    // edges per block in bucketA multi-split

typedef __attribute__((ext_vector_type(8))) short short8;
typedef __attribute__((ext_vector_type(4))) float f32x4;

__device__ __forceinline__ ushort f2bf(float f) {
    unsigned int u = __float_as_uint(f);
    unsigned int r = (u + 0x7FFFu + ((u >> 16) & 1u)) >> 16;   // RNE, finite inputs
    return (ushort)r;
}
__device__ __forceinline__ unsigned int cvt_pk_bf16(float lo, float hi) {
    unsigned int r;
    asm("v_cvt_pk_bf16_f32 %0, %1, %2" : "=v"(r) : "v"(lo), "v"(hi));
    return r;
}

// ---------------- weight prep ----------------
__global__ void prep_weights(const float* __restrict__ gW1, const float* __restrict__ lW1,
                             ushort* __restrict__ W1p, ushort* __restrict__ L1p) {
    int tid = threadIdx.x;
    for (int idx = tid; idx < 64 * 256; idx += 512) {
        int i = idx & 7, c = (idx >> 3) & 255, q = idx >> 11;
        int k = (q >> 2) * 32 + (q & 3) * 8 + i;
        W1p[idx] = f2bf(c < 128 ? gW1[k * 128 + c] : gW1[(64 + k) * 128 + (c - 128)]);
        L1p[idx] = f2bf(c < 128 ? lW1[k * 128 + c] : lW1[(128 + k) * 128 + (c - 128)]);
    }
}

// ---------------- CSR build: LDS multi-split -> fixed-capacity buckets -> in-LDS counting sort ----------------
__global__ __launch_bounds__(512) void bucketA_kernel(const int* __restrict__ eidx,
                                                      int* __restrict__ bcnt,
                                                      int2* __restrict__ btmp) {
    __shared__ int2 sp[EPB];         // 32 KB
    __shared__ ushort sb[EPB];       //  8 KB
    __shared__ ushort perm[EPB];     //  8 KB
    __shared__ int cnts[NBUCK];      //  2 KB
    __shared__ int lofs[NBUCK];      //  2 KB
    __shared__ int lcur[NBUCK];      //  2 KB
    const int tid = threadIdx.x;
    const int base = blockIdx.x * EPB;

    cnts[tid] = 0;
    __syncthreads();
    for (int i = tid; i < EPB; i += 512) {
        int d = eidx[EE + base + i], s = eidx[base + i];
        sp[i] = make_int2(s, d);
        int b = d / NPB;
        sb[i] = (ushort)b;
        atomicAdd(&cnts[b], 1);
    }
    __syncthreads();
    const int v = cnts[tid];
    lofs[tid] = v;
    __syncthreads();
    for (int o = 1; o < NBUCK; o <<= 1) {
        int u = (tid >= o) ? lofs[tid - o] : 0;
        __syncthreads();
        lofs[tid] += u;
        __syncthreads();
    }
    const int excl = lofs[tid] - v;
    lofs[tid] = excl;
    lcur[tid] = excl;
    const int mygbase = (v > 0) ? atomicAdd(&bcnt[tid * 16], v) : 0;
    __syncthreads();
    for (int i = tid; i < EPB; i += 512) {
        int pos = atomicAdd(&lcur[sb[i]], 1);
        perm[pos] = (ushort)i;
    }
    __syncthreads();
    {
        const int c = cnts[tid];
        const int lo = lofs[tid];
        int2* dst = btmp + (long)tid * CAP + mygbase;
        for (int j = 0; j < c; ++j) dst[j] = sp[perm[lo + j]];
    }
}

__global__ __launch_bounds__(512) void bucket_scan_kernel(const int* __restrict__ bcnt,
                                                          int* __restrict__ bbase) {
    __shared__ int s[NBUCK];
    const int t = threadIdx.x;
    int v = bcnt[t * 16];
    s[t] = v;
    __syncthreads();
    for (int o = 1; o < NBUCK; o <<= 1) {
        int u = (t >= o) ? s[t - o] : 0;
        __syncthreads();
        s[t] += u;
        __syncthreads();
    }
    bbase[t] = s[t] - v;   // exclusive
}

__global__ __launch_bounds__(256) void bucketB_kernel(const int2* __restrict__ btmp,
                                                      const int* __restrict__ bcnt,
                                                      const int* __restrict__ bbase,
                                                      int* __restrict__ offs,
                                                      int* __restrict__ csr) {
    __shared__ int lcnt[NPB];
    __shared__ int lofs[NPB];
    __shared__ int lcur[NPB];
    __shared__ int2 pairs[2048];
    const int bkt = blockIdx.x, tid = threadIdx.x;
    const int cnt = bcnt[bkt * 16];
    const int base = bbase[bkt];
    for (int j = tid; j < NPB; j += 256) lcnt[j] = 0;
    __syncthreads();
    for (int i = tid; i < cnt; i += 256) {
        int2 p = btmp[(long)bkt * CAP + i];
        if (i < 2048) pairs[i] = p;
        atomicAdd(&lcnt[p.y - bkt * NPB], 1);
    }
    __syncthreads();
    if (tid == 0) {
        int run = base;
        for (int j = 0; j < NPB; ++j) { lofs[j] = run; run += lcnt[j]; }
    }
    __syncthreads();
    for (int j = tid; j < NPB; j += 256) {
        lcur[j] = lofs[j];
        offs[bkt * NPB + j] = lofs[j];
    }
    if (bkt == NBUCK - 1 && tid == 0) offs[NN] = EE;
    __syncthreads();
    for (int i = tid; i < cnt; i += 256) {
        int2 p = (i < 2048) ? pairs[i] : btmp[(long)bkt * CAP + i];
        int pos = atomicAdd(&lcur[p.y - bkt * NPB], 1);
        csr[pos] = p.x;
    }
}

// ---------------- node-table GEMM: out[n][0:256] = bf16( x[n]@Wcat + bias_fold + T12[batch[n]] ) ----------------
__global__ __launch_bounds__(512) void pq_gemm(
        const float* __restrict__ x, const ushort* __restrict__ Wp,
        const float* __restrict__ bias1, const float* __restrict__ T12,
        const int* __restrict__ batch, ushort* __restrict__ out) {
    const int tid = threadIdx.x;
    const int w = tid >> 6, l = tid & 63, lr = l & 15, lg = l >> 4;
    const int node = blockIdx.x * 128 + w * 16 + lr;

    short8 xa[2];
#pragma unroll
    for (int ks = 0; ks < 2; ++ks) {
        const float4* bp = reinterpret_cast<const float4*>(x + (long)node * 64 + ks * 32 + lg * 8);
        float4 f0 = bp[0], f1 = bp[1];
        union { short8 s; unsigned int u[4]; } t;
        t.u[0] = cvt_pk_bf16(f0.x, f0.y);
        t.u[1] = cvt_pk_bf16(f0.z, f0.w);
        t.u[2] = cvt_pk_bf16(f1.x, f1.y);
        t.u[3] = cvt_pk_bf16(f1.z, f1.w);
        xa[ks] = t.s;
    }
    f32x4 acc[16];
#pragma unroll
    for (int t = 0; t < 16; ++t)
#pragma unroll
        for (int i = 0; i < 4; ++i)
            acc[t][i] = (t < 8) ? bias1[t * 16 + lg * 4 + i] : 0.f;
#pragma unroll
    for (int ks = 0; ks < 2; ++ks)
#pragma unroll
        for (int t = 0; t < 16; ++t) {
            short8 wf = *reinterpret_cast<const short8*>(Wp + (((ks * 4 + lg) * 256) + t * 16 + lr) * 8);
            acc[t] = __builtin_amdgcn_mfma_f32_16x16x32_bf16(wf, xa[ks], acc[t], 0, 0, 0);
        }
    if (T12) {
        const float* tp = T12 + (long)batch[node] * 256;
#pragma unroll
        for (int t = 0; t < 16; ++t)
#pragma unroll
            for (int i = 0; i < 4; ++i)
                acc[t][i] += tp[t * 16 + lg * 4 + i];
    }
#pragma unroll
    for (int t = 0; t < 16; ++t) {
        uint2 v;
        v.x = cvt_pk_bf16(acc[t][0], acc[t][1]);
        v.y = cvt_pk_bf16(acc[t][2], acc[t][3]);
        *reinterpret_cast<uint2*>(out + (long)node * 256 + t * 16 + lg * 4) = v;
    }
}

// ---------------- global edge pass (CSR): scalar control, 2 ch/lane, 8-deep gather batch ----------------
__global__ __launch_bounds__(256) void global_edge(
        const ushort* __restrict__ PQ, const int* __restrict__ csr,
        const int* __restrict__ offs, const float* __restrict__ e,
        const int* __restrict__ batch,
        float* __restrict__ hidpart, float* __restrict__ esumpart) {
    const int tid = threadIdx.x;
    const int w = tid >> 6, l = tid & 63;
    const int wid = blockIdx.x * 4 + w;
    const int node0 = __builtin_amdgcn_readfirstlane(wid * NPWG);
    const int slot = wid & (NS - 1);

    float accp0 = 0.f, accp1 = 0.f, eacc = 0.f;
    int curb = batch[node0];

    for (int n = 0; n < NPWG; ++n) {
        const int node = node0 + n;
        const int off  = offs[node];
        const int cnt  = offs[node + 1] - off;
        const int bb   = batch[node];
        const float ev = e[node];
        if (bb != curb) {
            float* hp = hidpart + (long)slot * (BB * 128) + curb * 128;
            atomicAdd(hp + 2 * l, accp0);
            atomicAdd(hp + 2 * l + 1, accp1);
            if (l == 0) atomicAdd(&esumpart[slot * BB + curb], eacc);
            accp0 = accp1 = eacc = 0.f;
            curb = bb;
        }
        if (cnt <= 0) continue;
        const unsigned int pdu = *reinterpret_cast<const unsigned int*>(PQ + (long)node * 256 + 2 * l);
        const float p0 = __uint_as_float(pdu << 16);
        const float p1 = __uint_as_float(pdu & 0xFFFF0000u);
        float h0 = 0.f, h1 = 0.f;
        int g = 0;
        for (; g + 8 <= cnt; g += 8) {          // 8 independent gathers in flight
            unsigned int qv[8];
#pragma unroll
            for (int k = 0; k < 8; ++k) {
                const int s = csr[off + g + k];
                qv[k] = *reinterpret_cast<const unsigned int*>(PQ + (long)s * 256 + 128 + 2 * l);
            }
#pragma unroll
            for (int k = 0; k < 8; ++k) {
                h0 += fmaxf(p0 + __uint_as_float(qv[k] << 16), 0.f);
                h1 += fmaxf(p1 + __uint_as_float(qv[k] & 0xFFFF0000u), 0.f);
            }
        }
        for (; g < cnt; ++g) {
            const int s = csr[off + g];
            const unsigned int qv = *reinterpret_cast<const unsigned int*>(PQ + (long)s * 256 + 128 + 2 * l);
            h0 += fmaxf(p0 + __uint_as_float(qv << 16), 0.f);
            h1 += fmaxf(p1 + __uint_as_float(qv & 0xFFFF0000u), 0.f);
        }
        accp0 += ev * h0; accp1 += ev * h1; eacc += ev * (float)cnt;
    }
    {   // final flush
        float* hp = hidpart + (long)slot * (BB * 128) + curb * 128;
        atomicAdd(hp + 2 * l, accp0);
        atomicAdd(hp + 2 * l + 1, accp1);
        if (l == 0) atomicAdd(&esumpart[slot * BB + curb], eacc);
    }
}

// ---------------- fused: hidsum reduce -> pooled (LDS only) -> T12 ----------------
__global__ __launch_bounds__(256) void pooled_t12_kernel(
        const float* __restrict__ hidpart, const float* __restrict__ esumpart,
        const float* __restrict__ gW2, const float* __restrict__ gb2,
        const float* __restrict__ lW1, float* __restrict__ T12) {
    __shared__ float hs[128];
    __shared__ float qacc[4][64];
    __shared__ float pb[64];
    __shared__ float esv;
    const int b = blockIdx.x, tid = threadIdx.x;
    if (tid < 128) {
        float s = 0.f;
        for (int sl = 0; sl < NS; ++sl) s += hidpart[(long)sl * (BB * 128) + b * 128 + tid];
        hs[tid] = s;
    } else if (tid == 128) {
        float s = 0.f;
        for (int sl = 0; sl < NS; ++sl) s += esumpart[sl * BB + b];
        esv = s;
    }
    __syncthreads();
    {
        int col = tid & 63, qr = tid >> 6;
        float a = 0.f;
        for (int k = qr * 32; k < qr * 32 + 32; ++k) a += hs[k] * gW2[k * 64 + col];
        qacc[qr][col] = a;
    }
    __syncthreads();
    if (tid < 64) pb[tid] = qacc[0][tid] + qacc[1][tid] + qacc[2][tid] + qacc[3][tid] + esv * gb2[tid];
    __syncthreads();
    const float* col = (tid < 128) ? (lW1 + 64 * 128 + tid) : (lW1 + 192 * 128 + (tid - 128));
    float acc = 0.f;
    for (int k = 0; k < 64; ++k) acc += pb[k] * col[k * 128];
    T12[b * 256 + tid] = acc;
}

// ---------------- local edge pass (CSR): scalar control, 2 ch/lane, 8-deep gather batch ----------------
__global__ __launch_bounds__(256) void local_edge(
        const ushort* __restrict__ PQL, const int* __restrict__ csr,
        const int* __restrict__ offs, const float* __restrict__ lW2,
        const float* __restrict__ lb2, float* __restrict__ out) {
    const int tid = threadIdx.x;
    const int w = tid >> 6, l = tid & 63;
    const int wid = blockIdx.x * 4 + w;
    const int node0 = __builtin_amdgcn_readfirstlane(wid * NPWL);
    const float w20 = lW2[2 * l], w21 = lW2[2 * l + 1];
    const float b2v = lb2[0];

    for (int n = 0; n < NPWL; ++n) {
        const int node = node0 + n;
        const int off = offs[node];
        const int cnt = offs[node + 1] - off;
        float dacc = 0.f;
        if (cnt > 0) {
            const unsigned int pdu = *reinterpret_cast<const unsigned int*>(PQL + (long)node * 256 + 2 * l);
            const float p0 = __uint_as_float(pdu << 16);
            const float p1 = __uint_as_float(pdu & 0xFFFF0000u);
            int g = 0;
            for (; g + 8 <= cnt; g += 8) {
                unsigned int qv[8];
#pragma unroll
                for (int k = 0; k < 8; ++k) {
                    const int s = csr[off + g + k];
                    qv[k] = *reinterpret_cast<const unsigned int*>(PQL + (long)s * 256 + 128 + 2 * l);
                }
#pragma unroll
                for (int k = 0; k < 8; ++k) {
                    dacc += fmaxf(p0 + __uint_as_float(qv[k] << 16), 0.f) * w20
                          + fmaxf(p1 + __uint_as_float(qv[k] & 0xFFFF0000u), 0.f) * w21;
                }
            }
            for (; g < cnt; ++g) {
                const int s = csr[off + g];
                const unsigned int qv = *reinterpret_cast<const unsigned int*>(PQL + (long)s * 256 + 128 + 2 * l);
                dacc += fmaxf(p0 + __uint_as_float(qv << 16), 0.f) * w20
                      + fmaxf(p1 + __uint_as_float(qv & 0xFFFF0000u), 0.f) * w21;
            }
            dacc += __shfl_xor(dacc, 1, 64);
            dacc += __shfl_xor(dacc, 2, 64);
            dacc += __shfl_xor(dacc, 4, 64);
            dacc += __shfl_xor(dacc, 8, 64);
            dacc += __shfl_xor(dacc, 16, 64);
            dacc += __shfl_xor(dacc, 32, 64);
        }
        if (l == 0) out[node] = dacc + (float)cnt * b2v;
    }
}

extern "C" void kernel_launch(void* const* d_in, const int* in_sizes, int n_in,
                              void* d_out, int out_size, void* d_ws, size_t ws_size,
                              hipStream_t stream) {
    const float* x   = (const float*)d_in[0];
    const float* e   = (const float*)d_in[1];
    const int*   ei  = (const int*)d_in[2];
    const int*   bat = (const int*)d_in[3];
    const float* gW1 = (const float*)d_in[4];
    const float* gb1 = (const float*)d_in[5];
    const float* gW2 = (const float*)d_in[6];
    const float* gb2 = (const float*)d_in[7];
    const float* lW1 = (const float*)d_in[8];
    const float* lb1 = (const float*)d_in[9];
    const float* lW2 = (const float*)d_in[10];
    const float* lb2 = (const float*)d_in[11];

    char* ws = (char*)d_ws;
    ushort* W1p     = (ushort*)(ws);                     //    32768 B
    ushort* L1p     = (ushort*)(ws + 32768);             //    32768 B
    float*  T12     = (float*)(ws + 65536);              //    65536 B
    float*  esumpart= (float*)(ws + 131072);             //     8192 B
    float*  hidpart = (float*)(ws + 139264);             //  1048576 B
    int*    offs    = (int*)(ws + 1187840);              //   204832 B (51201 ints)
    int*    bcnt    = (int*)(ws + 1392672);              //    32768 B (512 line-padded)
    int*    bbase   = (int*)(ws + 1425440);              //     2048 B
    int*    csr     = (int*)(ws + 1427488);              //  3276800 B
    ushort* PQ      = (ushort*)(ws + 4704288);           // 26214400 B (btmp overlays; reused for PQL)
    int2*   btmp    = (int2*)PQ;                         // 512*4096*8 = 16777216 B, consumed before pq_gemm

    hipMemsetAsync(bcnt, 0, 32768, stream);
    hipMemsetAsync(esumpart, 0, 8192 + 1048576, stream);           // esumpart + hidpart
    hipMemsetAsync(d_out, 0, (size_t)out_size * sizeof(float), stream);

    prep_weights<<<1, 512, 0, stream>>>(gW1, lW1, W1p, L1p);
    bucketA_kernel<<<EE / EPB, 512, 0, stream>>>(ei, bcnt, btmp);
    bucket_scan_kernel<<<1, NBUCK, 0, stream>>>(bcnt, bbase);
    bucketB_kernel<<<NBUCK, 256, 0, stream>>>(btmp, bcnt, bbase, offs, csr);

    pq_gemm<<<NN / 128, 512, 0, stream>>>(x, W1p, gb1, nullptr, bat, PQ);
    global_edge<<<NN / (4 * NPWG), 256, 0, stream>>>(PQ, csr, offs, e, bat, hidpart, esumpart);
    pooled_t12_kernel<<<BB, 256, 0, stream>>>(hidpart, esumpart, gW2, gb2, lW1, T12);
    pq_gemm<<<NN / 128, 512, 0, stream>>>(x, L1p, lb1, T12, bat, PQ);   // -> PQL
    local_edge<<<NN / (4 * NPWL), 256, 0, stream>>>(PQ, csr, offs, lW2, lb2, (float*)d_out);
}